// Round 9
// baseline (151.017 us; speedup 1.0000x reference)
//
#include <hip/hip_runtime.h>
#include <math.h>

#define NWIRES 6
#define DIM 64
#define NTOK 32768            // B*T = 16*2048
#define NBATCH 16
#define TPB 2048              // tokens per batch
#define NMOM 16               // Taylor order: exp(az), |az|<=sqrt(6); rem ~8e-8
#define SQRT6F 2.4494897427831781f
#define CSTRIDE 160           // per-circuit table stride (floats)

// ---------------------------------------------------------------------------
// Kernel 0: per-circuit tables.
// T[0..63] = cos(d_b), T[64..127] = sin(d_b), d_b = sum_j (th_rx[j]/2)*(-1)^{b_j}
// (RX layer = W diag(e^{-id}) W / 64). T[128+..] = RY {cos,sin} pairs.
// ---------------------------------------------------------------------------
__global__ void qsa_prep(const float* __restrict__ pq,
                         const float* __restrict__ pk,
                         const float* __restrict__ pv,
                         float* __restrict__ cs) {
    int b = threadIdx.x;      // 64 threads
    for (int circ = 0; circ < 3; ++circ) {
        const float* p = (circ == 0) ? pq : (circ == 1 ? pk : pv);
        float* T = cs + circ * CSTRIDE;
        float d = 0.f;
#pragma unroll
        for (int j = 0; j < 6; ++j)
            d += 0.5f * p[j] * ((b & (32 >> j)) ? -1.f : 1.f);
        float sd, cd;
        sincosf(d, &sd, &cd);
        T[b] = cd;
        T[64 + b] = sd;
        if (b < 12) {                       // p[6..11]=RY0, p[12..17]=RY1
            float s, c;
            sincosf(0.5f * p[6 + b], &s, &c);
            T[128 + b * 2 + 0] = c;
            T[128 + b * 2 + 1] = s;
        }
    }
}

// ---------------------------------------------------------------------------
// Real-gate helpers (compile-time indices; used only in tiny prepM kernel).
// ---------------------------------------------------------------------------
template<int M>
__device__ __forceinline__ void ryr(float* v, float c, float s) {
#pragma unroll
    for (int i = 0; i < DIM; ++i) {
        if (i & M) continue;
        int j = i | M;
        float a = v[i], b = v[j];
        v[i] = c * a - s * b;
        v[j] = s * a + c * b;
    }
}

template<int MC, int MT>
__device__ __forceinline__ void cnr(float* v) {
#pragma unroll
    for (int i = 0; i < DIM; ++i) {
        if (!(i & MC) || (i & MT)) continue;
        int j = i | MT;
        float t = v[i]; v[i] = v[j]; v[j] = t;
    }
}

// ---------------------------------------------------------------------------
// Kernel 0b: build M_cos, M_sin per circuit (row-major 64x64 each).
// Column b of (G*W) = G applied to W's b-th sign column; then scale col b by
// cosd[b] / sind[b].  G = RY1 * CNOT-ring * RY0 (real orthogonal).
// Only 3 blocks -> waves_per_eu(1,1) gives full register budget, no spill.
// ---------------------------------------------------------------------------
__global__ __attribute__((amdgpu_waves_per_eu(1, 1)))
__launch_bounds__(64) void qsa_prepM(const float* __restrict__ cs,
                                     float* __restrict__ Mmat) {
    int c = blockIdx.x, b = threadIdx.x;
    const float* T = cs + c * CSTRIDE;
    const float* P = T + 128;
    float st[DIM];
#pragma unroll
    for (int i = 0; i < DIM; ++i)
        st[i] = (__popc(i & b) & 1) ? -1.f : 1.f;   // W column b
    // G = RY0 layer, CNOT ring, RY1 layer
    ryr<32>(st, P[0],  P[1]);
    ryr<16>(st, P[2],  P[3]);
    ryr< 8>(st, P[4],  P[5]);
    ryr< 4>(st, P[6],  P[7]);
    ryr< 2>(st, P[8],  P[9]);
    ryr< 1>(st, P[10], P[11]);
    cnr<32,16>(st); cnr<16,8>(st); cnr<8,4>(st);
    cnr<4,2>(st);   cnr<2,1>(st);  cnr<1,32>(st);
    ryr<32>(st, P[12], P[13]);
    ryr<16>(st, P[14], P[15]);
    ryr< 8>(st, P[16], P[17]);
    ryr< 4>(st, P[18], P[19]);
    ryr< 2>(st, P[20], P[21]);
    ryr< 1>(st, P[22], P[23]);
    float cb = T[b], sb = T[64 + b];
    float* Mc = Mmat + (size_t)c * 8192;            // [row*64+col]
    float* Ms = Mc + 4096;
#pragma unroll
    for (int r = 0; r < DIM; ++r) {
        Mc[r * 64 + b] = st[r] * cb;
        Ms[r * 64 + b] = st[r] * sb;
    }
}

// ---------------------------------------------------------------------------
// Kernel 1: sim. One thread per token; blockIdx.y = circuit.
// y = Wx (one in-register Walsh), n = 64*|y|^2 (M/8 is orthogonal).
// Row-streamed dots: dc = M_cos[r].y, ds = M_sin[r].y via an unrolled inner
// 64-dot with 8 independent accumulators (dep distance >> FMA latency), outer
// row loop NOT unrolled (small I$ body). M rows are wave-uniform -> s_load.
// S_w = sum over rows with bit_w==0 of dc^2+ds^2;  z_w = (2 S_w - n)/n.
// q/k circuits need only rows 0..31 (S_0).
// R8 post-mortem: the fully-unrolled gate cascade scheduled chain-serial
// (VALUBusy 16%) regardless of occupancy pins; this looped form controls ILP
// explicitly. waves_per_eu(2,2): allocs 128 VGPR (observed R4), live ~85 fits.
// ---------------------------------------------------------------------------
__global__ __attribute__((amdgpu_waves_per_eu(2, 2)))
__launch_bounds__(64) void qsa_sim(
        const float* __restrict__ x,
        const float* __restrict__ Mmat,
        float* __restrict__ zq,
        float* __restrict__ kv) {
    int t = blockIdx.x * 64 + threadIdx.x;
    int circ = blockIdx.y;
    const float* Mc = Mmat + (size_t)circ * 8192;
    const float* Ms = Mc + 4096;

    float y[DIM];
    const float4* xp4 = (const float4*)(x + (size_t)t * DIM);
#pragma unroll
    for (int k = 0; k < DIM / 4; ++k) {
        float4 q = xp4[k];
        y[4*k+0] = q.x; y[4*k+1] = q.y; y[4*k+2] = q.z; y[4*k+3] = q.w;
    }
    // Walsh: y = W x
#pragma unroll
    for (int M = 32; M >= 1; M >>= 1) {
#pragma unroll
        for (int i = 0; i < DIM; ++i) {
            if (i & M) continue;
            int j = i | M;
            float a = y[i], b = y[j];
            y[i] = a + b;
            y[j] = a - b;
        }
    }
    // n = |r|^2+|s|^2 = 64*|y|^2
    float n0 = 0.f, n1 = 0.f, n2 = 0.f, n3 = 0.f;
#pragma unroll
    for (int k = 0; k < DIM; k += 4) {
        n0 += y[k]*y[k];   n1 += y[k+1]*y[k+1];
        n2 += y[k+2]*y[k+2]; n3 += y[k+3]*y[k+3];
    }
    float n = 64.f * ((n0 + n1) + (n2 + n3));
    float inv = 1.0f / n;

    if (circ < 2) {
        float s0 = 0.f;
#pragma unroll 1
        for (int r = 0; r < 32; ++r) {
            const float* cr = Mc + (r << 6);
            const float* sr = Ms + (r << 6);
            float c0=0.f,c1=0.f,c2=0.f,c3=0.f,d0=0.f,d1=0.f,d2=0.f,d3=0.f;
#pragma unroll
            for (int k = 0; k < DIM; k += 4) {
                c0 += cr[k]  *y[k];   d0 += sr[k]  *y[k];
                c1 += cr[k+1]*y[k+1]; d1 += sr[k+1]*y[k+1];
                c2 += cr[k+2]*y[k+2]; d2 += sr[k+2]*y[k+2];
                c3 += cr[k+3]*y[k+3]; d3 += sr[k+3]*y[k+3];
            }
            float dc = (c0 + c1) + (c2 + c3);
            float ds = (d0 + d1) + (d2 + d3);
            s0 += dc * dc + ds * ds;
        }
        float z0 = (2.f * s0 - n) * inv;
        if (circ == 0) zq[t] = SQRT6F * z0;          // a_t, natural-exp scale
        else           kv[(size_t)t * 8] = z0;
    } else {
        float a0=0.f,a1=0.f,a2=0.f,a3=0.f,a4=0.f,a5=0.f;
#pragma unroll 1
        for (int r = 0; r < 64; ++r) {
            const float* cr = Mc + (r << 6);
            const float* sr = Ms + (r << 6);
            float c0=0.f,c1=0.f,c2=0.f,c3=0.f,d0=0.f,d1=0.f,d2=0.f,d3=0.f;
#pragma unroll
            for (int k = 0; k < DIM; k += 4) {
                c0 += cr[k]  *y[k];   d0 += sr[k]  *y[k];
                c1 += cr[k+1]*y[k+1]; d1 += sr[k+1]*y[k+1];
                c2 += cr[k+2]*y[k+2]; d2 += sr[k+2]*y[k+2];
                c3 += cr[k+3]*y[k+3]; d3 += sr[k+3]*y[k+3];
            }
            float dc = (c0 + c1) + (c2 + c3);
            float ds = (d0 + d1) + (d2 + d3);
            float p = dc * dc + ds * ds;
            if (!(r & 32)) a0 += p;
            if (!(r & 16)) a1 += p;
            if (!(r &  8)) a2 += p;
            if (!(r &  4)) a3 += p;
            if (!(r &  2)) a4 += p;
            if (!(r &  1)) a5 += p;
        }
        float* o = kv + (size_t)t * 8;
        o[1] = (2.f*a0 - n) * inv;
        o[2] = (2.f*a1 - n) * inv;
        o[3] = (2.f*a2 - n) * inv;
        o[4] = (2.f*a3 - n) * inv;
        o[5] = (2.f*a4 - n) * inv;
        o[6] = (2.f*a5 - n) * inv;
        o[7] = 0.f;
    }
}

// ---------------------------------------------------------------------------
// Kernel 2: partial power moments per (batch, chunk-of-256).
// S_m = sum z^m, H_{m,w} = sum z^m * v_w, m=0..15.  112 register accumulators,
// butterfly-reduced across the wave; lane 0 stores 112 floats.
// ---------------------------------------------------------------------------
__global__ __attribute__((amdgpu_waves_per_eu(1, 2)))
__launch_bounds__(64) void qsa_moments_partial(
        const float* __restrict__ kv,
        float* __restrict__ mpart) {
    int blk = blockIdx.x;             // 16 batches * 8 chunks
    int b = blk >> 3, c = blk & 7;
    int lane = threadIdx.x;
    float S[NMOM], H[NMOM][6];
#pragma unroll
    for (int m = 0; m < NMOM; ++m) {
        S[m] = 0.f;
#pragma unroll
        for (int w = 0; w < 6; ++w) H[m][w] = 0.f;
    }
    const float* base = kv + ((size_t)(b * TPB + c * 256)) * 8;
#pragma unroll
    for (int r = 0; r < 4; ++r) {
        const float4* e = (const float4*)(base + (size_t)(r * 64 + lane) * 8);
        float4 e0 = e[0], e1 = e[1];
        float z = e0.x;
        float v0 = e0.y, v1 = e0.z, v2 = e0.w, v3 = e1.x, v4 = e1.y, v5 = e1.z;
        float pw = 1.f;
#pragma unroll
        for (int m = 0; m < NMOM; ++m) {
            S[m] += pw;
            H[m][0] += pw * v0; H[m][1] += pw * v1; H[m][2] += pw * v2;
            H[m][3] += pw * v3; H[m][4] += pw * v4; H[m][5] += pw * v5;
            pw *= z;
        }
    }
#pragma unroll
    for (int d = 32; d >= 1; d >>= 1) {
#pragma unroll
        for (int m = 0; m < NMOM; ++m) {
            S[m] += __shfl_xor(S[m], d, 64);
#pragma unroll
            for (int w = 0; w < 6; ++w) H[m][w] += __shfl_xor(H[m][w], d, 64);
        }
    }
    if (lane == 0) {
        float* o = mpart + (size_t)blk * 112;
#pragma unroll
        for (int m = 0; m < NMOM; ++m) {
            float* om = o + m * 7;
            om[0] = S[m];
            om[1] = H[m][0]; om[2] = H[m][1]; om[3] = H[m][2];
            om[4] = H[m][3]; om[5] = H[m][4]; om[6] = H[m][5];
        }
    }
}

// ---------------------------------------------------------------------------
// Kernel 3: fused combine + per-token evaluation (one block = 256 tokens).
// den = sum_m p_m S_m, out_w = sum_m p_m H_mw, p_m = a^m/m!.
// ---------------------------------------------------------------------------
__global__ __launch_bounds__(256) void qsa_eval(
        const float* __restrict__ zq,
        const float* __restrict__ mpart,
        float* __restrict__ out) {
    __shared__ float sm[112];
    int bk = blockIdx.x;                      // 128 blocks
    int b = bk >> 3;                          // 8 blocks per batch
    int tid = threadIdx.x;
    if (tid < 112) {
        float s = 0.f;
#pragma unroll
        for (int c = 0; c < 8; ++c) s += mpart[(size_t)(b * 8 + c) * 112 + tid];
        sm[tid] = s;
    }
    __syncthreads();

    int t = bk * 256 + tid;
    float a = zq[t];
    float den = 0.f, o0 = 0.f, o1 = 0.f, o2 = 0.f, o3 = 0.f, o4 = 0.f, o5 = 0.f;
    float pw = 1.f;
#pragma unroll
    for (int m = 0; m < NMOM; ++m) {
        const float* mm = sm + m * 7;
        den += pw * mm[0];
        o0 += pw * mm[1]; o1 += pw * mm[2]; o2 += pw * mm[3];
        o3 += pw * mm[4]; o4 += pw * mm[5]; o5 += pw * mm[6];
        pw *= a * (1.0f / (m + 1));           // p_{m+1} = p_m * a/(m+1)
    }
    float inv = 1.0f / den;
    float* o = out + (size_t)t * 6;
    float2* o2p = (float2*)o;                 // t*24B is 8-aligned
    o2p[0] = make_float2(o0 * inv, o1 * inv);
    o2p[1] = make_float2(o2 * inv, o3 * inv);
    o2p[2] = make_float2(o4 * inv, o5 * inv);
}

// ---------------------------------------------------------------------------
extern "C" void kernel_launch(void* const* d_in, const int* in_sizes, int n_in,
                              void* d_out, int out_size, void* d_ws, size_t ws_size,
                              hipStream_t stream) {
    const float* x  = (const float*)d_in[0];
    const float* pq = (const float*)d_in[1];
    const float* pk = (const float*)d_in[2];
    const float* pv = (const float*)d_in[3];
    float* w = (float*)d_ws;
    // ws (floats): cs[480] | M[3*8192] | zq[32768] | kv[262144] | mpart[14336]
    float* cs    = w;
    float* Mmat  = w + 512;
    float* zq    = Mmat + 3 * 8192;
    float* kv    = zq + NTOK;
    float* mpart = kv + NTOK * 8;
    float* out   = (float*)d_out;

    qsa_prep<<<1, 64, 0, stream>>>(pq, pk, pv, cs);
    qsa_prepM<<<3, 64, 0, stream>>>(cs, Mmat);
    qsa_sim<<<dim3(NTOK / 64, 3), 64, 0, stream>>>(x, Mmat, zq, kv);
    qsa_moments_partial<<<NBATCH * 8, 64, 0, stream>>>(kv, mpart);
    qsa_eval<<<NTOK / 256, 256, 0, stream>>>(zq, mpart, out);
}

// Round 10
// 113.024 us; speedup vs baseline: 1.3361x; 1.3361x over previous
//
#include <hip/hip_runtime.h>
#include <math.h>

#define NWIRES 6
#define DIM 64
#define NTOK 32768            // B*T = 16*2048
#define NBATCH 16
#define TPB 2048              // tokens per batch
#define NMOM 16               // Taylor order: exp(az), |az|<=sqrt(6); rem ~8e-8
#define SQRT6F 2.4494897427831781f
#define CSTRIDE 160           // per-circuit angle-table stride (floats)
#define XPAD 72               // padded LDS row (elements); 72*2B=144B, 16B-aligned rows

typedef short bf16x8 __attribute__((ext_vector_type(8)));
typedef float f32x4  __attribute__((ext_vector_type(4)));

__device__ __forceinline__ unsigned f2bfbits(float f) {   // RNE fp32->bf16 bits
    unsigned u = __float_as_uint(f);
    return (u + 0x7FFF + ((u >> 16) & 1)) >> 16;
}
__device__ __forceinline__ float bfbits2f(unsigned b) {
    return __uint_as_float(b << 16);
}

// ---------------------------------------------------------------------------
// Kernel 0: angle tables. T[0..63]=cos(d_b), T[64..127]=sin(d_b),
// d_b = sum_j (th_rx[j]/2)(-1)^{b_j}; T[128+..] = RY {cos,sin} pairs.
// ---------------------------------------------------------------------------
__global__ void qsa_prep(const float* __restrict__ pq,
                         const float* __restrict__ pk,
                         const float* __restrict__ pv,
                         float* __restrict__ cs) {
    int b = threadIdx.x;      // 64 threads
    for (int circ = 0; circ < 3; ++circ) {
        const float* p = (circ == 0) ? pq : (circ == 1 ? pk : pv);
        float* T = cs + circ * CSTRIDE;
        float d = 0.f;
#pragma unroll
        for (int j = 0; j < 6; ++j)
            d += 0.5f * p[j] * ((b & (32 >> j)) ? -1.f : 1.f);
        float sd, cd;
        sincosf(d, &sd, &cd);
        T[b] = cd;
        T[64 + b] = sd;
        if (b < 12) {
            float s, c;
            sincosf(0.5f * p[6 + b], &s, &c);
            T[128 + b * 2 + 0] = c;
            T[128 + b * 2 + 1] = s;
        }
    }
}

// ---------------------------------------------------------------------------
// Real-gate helpers for prepM (compile-time indices).
// ---------------------------------------------------------------------------
template<int M>
__device__ __forceinline__ void ryr(float* v, float c, float s) {
#pragma unroll
    for (int i = 0; i < DIM; ++i) {
        if (i & M) continue;
        int j = i | M;
        float a = v[i], b = v[j];
        v[i] = c * a - s * b;
        v[j] = s * a + c * b;
    }
}
template<int MC, int MT>
__device__ __forceinline__ void cnr(float* v) {
#pragma unroll
    for (int i = 0; i < DIM; ++i) {
        if (!(i & MC) || (i & MT)) continue;
        int j = i | MT;
        float t = v[i]; v[i] = v[j]; v[j] = t;
    }
}

// ---------------------------------------------------------------------------
// Kernel 0b: build A = [A_c; A_s] per circuit, split to bf16 hi/lo.
// A_c = G * W * diag(cosd) * W   (A_s with sind).  Thread k builds column k:
// u_i = cd_i * (-1)^{popc(i&k)}  (= diag(cd) W e_k), in-thread Walsh -> W u,
// then G cascade (RY0, CNOT ring, RY1) -> column of A_c.  Math path identical
// to the R7/R9-verified pipeline.  Layout: Apack[circ][hi=0/lo=1][128][64] bf16.
// ---------------------------------------------------------------------------
__global__ __attribute__((amdgpu_waves_per_eu(1, 1)))
__launch_bounds__(64) void qsa_prepM(const float* __restrict__ cs,
                                     unsigned short* __restrict__ Apack) {
    int c = blockIdx.x, k = threadIdx.x;
    const float* T = cs + c * CSTRIDE;
    const float* P = T + 128;
    unsigned short* Ah = Apack + (size_t)c * 16384;
    unsigned short* Al = Ah + 8192;
    for (int ph = 0; ph < 2; ++ph) {          // 0: cos rows 0..63, 1: sin rows 64..127
        float v[DIM];
#pragma unroll
        for (int i = 0; i < DIM; ++i) {
            float sgn = (__popc(i & k) & 1) ? -1.f : 1.f;
            v[i] = T[ph * 64 + i] * sgn;
        }
        // Walsh
#pragma unroll
        for (int M = 32; M >= 1; M >>= 1) {
#pragma unroll
            for (int i = 0; i < DIM; ++i) {
                if (i & M) continue;
                int j = i | M;
                float a = v[i], b = v[j];
                v[i] = a + b; v[j] = a - b;
            }
        }
        // G = RY0, CNOT ring, RY1
        ryr<32>(v, P[0],  P[1]);
        ryr<16>(v, P[2],  P[3]);
        ryr< 8>(v, P[4],  P[5]);
        ryr< 4>(v, P[6],  P[7]);
        ryr< 2>(v, P[8],  P[9]);
        ryr< 1>(v, P[10], P[11]);
        cnr<32,16>(v); cnr<16,8>(v); cnr<8,4>(v);
        cnr<4,2>(v);   cnr<2,1>(v);  cnr<1,32>(v);
        ryr<32>(v, P[12], P[13]);
        ryr<16>(v, P[14], P[15]);
        ryr< 8>(v, P[16], P[17]);
        ryr< 4>(v, P[18], P[19]);
        ryr< 2>(v, P[20], P[21]);
        ryr< 1>(v, P[22], P[23]);
#pragma unroll
        for (int r = 0; r < DIM; ++r) {
            unsigned hb = f2bfbits(v[r]);
            unsigned lb = f2bfbits(v[r] - bfbits2f(hb));
            int row = ph * 64 + r;
            Ah[row * 64 + k] = (unsigned short)hb;
            Al[row * 64 + k] = (unsigned short)lb;
        }
    }
}

// ---------------------------------------------------------------------------
// Kernel 1: MFMA sim.  Per block: 64-token tile, one circuit (blockIdx.y).
// C[r,t] = sum_k A[r,k] x[t,k]  via mfma_f32_16x16x32_bf16, bf16x3 split:
// Ah*Xh + Ah*Xl + Al*Xh (fp32 accumulate).  X staged in LDS (hi/lo, padded
// rows -> 2-way-free banks); A fragments read from global (96 KB total, hot
// in L1/L2, shared by every wave on the device).
// Fragment layouts (m89/m120-verified): A-op: m=lane&15, k=(lane>>4)*8+j;
// B-op (mirror): n=lane&15, k=(lane>>4)*8+j;  D: col=lane&15, row=(lane>>4)*4+reg.
// Wave w handles tokens [w*16,w*16+16), all 128 rows (8 m-tiles).
// Epilogue: p_r = C[r,t]^2 + C[r+64,t]^2 (same lane: m-tiles mt and mt+4);
// masked sums: r-bits [5:4]=mt (compile-time), [3:2]=q=lane>>4 (flag FMA),
// [1:0]=reg (compile-time); combine 4 lanes/token via 2 shuffles per value.
// ---------------------------------------------------------------------------
__global__ __attribute__((amdgpu_waves_per_eu(2, 4)))
__launch_bounds__(256) void qsa_sim(
        const float* __restrict__ x,
        const unsigned short* __restrict__ Apack,
        float* __restrict__ zq,
        float* __restrict__ kv) {
    __shared__ unsigned short sXh[64 * XPAD];
    __shared__ unsigned short sXl[64 * XPAD];
    int tid = threadIdx.x;
    int tbase = blockIdx.x * 64;
    int circ = blockIdx.y;
    const unsigned short* Ah = Apack + (size_t)circ * 16384;
    const unsigned short* Al = Ah + 8192;

    // ---- stage X tile (64 tokens x 64 feats), convert fp32 -> bf16 hi/lo ----
#pragma unroll
    for (int rr = 0; rr < 4; ++rr) {
        int i = rr * 256 + tid;               // 1024 float4 chunks
        int tok = i >> 4, ch = i & 15;        // chunk = 4 consecutive feats
        float4 q = ((const float4*)(x + ((size_t)(tbase + tok)) * 64))[ch];
        unsigned h0 = f2bfbits(q.x), h1 = f2bfbits(q.y),
                 h2 = f2bfbits(q.z), h3 = f2bfbits(q.w);
        unsigned l0 = f2bfbits(q.x - bfbits2f(h0)),
                 l1 = f2bfbits(q.y - bfbits2f(h1)),
                 l2 = f2bfbits(q.z - bfbits2f(h2)),
                 l3 = f2bfbits(q.w - bfbits2f(h3));
        uint2 hp = make_uint2(h0 | (h1 << 16), h2 | (h3 << 16));
        uint2 lp = make_uint2(l0 | (l1 << 16), l2 | (l3 << 16));
        *(uint2*)(&sXh[tok * XPAD + ch * 4]) = hp;   // byte addr 16B-pattern, 8B aligned
        *(uint2*)(&sXl[tok * XPAD + ch * 4]) = lp;
    }
    __syncthreads();

    int lane = tid & 63, wv = tid >> 6;
    int q4 = lane >> 4, c16 = lane & 15;
    int mytok = wv * 16 + c16;                // token (B-op col n)

    // X fragments (kept in regs, reused across all 8 m-tiles)
    bf16x8 xh[2], xl[2];
#pragma unroll
    for (int ks = 0; ks < 2; ++ks) {
        int el = mytok * XPAD + ks * 32 + q4 * 8;
        xh[ks] = *(const bf16x8*)(&sXh[el]);
        xl[ks] = *(const bf16x8*)(&sXl[el]);
    }

    f32x4 acc[8];
#pragma unroll
    for (int mt = 0; mt < 8; ++mt) acc[mt] = (f32x4){0.f, 0.f, 0.f, 0.f};

#pragma unroll
    for (int mt = 0; mt < 8; ++mt) {
        int r = mt * 16 + c16;                // A-op row m
#pragma unroll
        for (int ks = 0; ks < 2; ++ks) {
            const bf16x8 ah = *(const bf16x8*)(Ah + r * 64 + ks * 32 + q4 * 8);
            const bf16x8 al = *(const bf16x8*)(Al + r * 64 + ks * 32 + q4 * 8);
            acc[mt] = __builtin_amdgcn_mfma_f32_16x16x32_bf16(ah, xh[ks], acc[mt], 0, 0, 0);
            acc[mt] = __builtin_amdgcn_mfma_f32_16x16x32_bf16(ah, xl[ks], acc[mt], 0, 0, 0);
            acc[mt] = __builtin_amdgcn_mfma_f32_16x16x32_bf16(al, xh[ks], acc[mt], 0, 0, 0);
        }
    }

    // ---- epilogue: p_r = dc^2 + ds^2, masked sums, 4-lane combine ----
    float n = 0.f, s0 = 0.f, s1 = 0.f, s2 = 0.f, s3 = 0.f, s4 = 0.f, s5 = 0.f;
    float f2 = (q4 < 2) ? 1.f : 0.f;          // r bit3 == 0
    float f3 = (q4 & 1) ? 0.f : 1.f;          // r bit2 == 0
#pragma unroll
    for (int mt = 0; mt < 4; ++mt) {
#pragma unroll
        for (int rg = 0; rg < 4; ++rg) {
            float dc = acc[mt][rg];           // row r = mt*16 + q4*4 + rg
            float ds = acc[mt + 4][rg];       // row r + 64
            float p = dc * dc + ds * ds;
            n += p;
            if (!(mt & 2)) s0 += p;           // bit5
            if (!(mt & 1)) s1 += p;           // bit4
            s2 += f2 * p;                     // bit3
            s3 += f3 * p;                     // bit2
            if (!(rg & 2)) s4 += p;           // bit1
            if (!(rg & 1)) s5 += p;           // bit0
        }
    }
#pragma unroll
    for (int d = 16; d <= 32; d <<= 1) {
        n  += __shfl_xor(n,  d, 64);
        s0 += __shfl_xor(s0, d, 64);
        s1 += __shfl_xor(s1, d, 64);
        s2 += __shfl_xor(s2, d, 64);
        s3 += __shfl_xor(s3, d, 64);
        s4 += __shfl_xor(s4, d, 64);
        s5 += __shfl_xor(s5, d, 64);
    }
    if (q4 == 0) {
        int t = tbase + mytok;
        float inv = 1.0f / n;
        if (circ == 0) {
            zq[t] = SQRT6F * (2.f * s0 - n) * inv;    // a_t, natural-exp scale
        } else if (circ == 1) {
            kv[(size_t)t * 8] = (2.f * s0 - n) * inv;
        } else {
            float* o = kv + (size_t)t * 8;
            o[1] = (2.f*s0 - n) * inv;
            o[2] = (2.f*s1 - n) * inv;
            o[3] = (2.f*s2 - n) * inv;
            o[4] = (2.f*s3 - n) * inv;
            o[5] = (2.f*s4 - n) * inv;
            o[6] = (2.f*s5 - n) * inv;
            o[7] = 0.f;
        }
    }
}

// ---------------------------------------------------------------------------
// Kernel 2: partial power moments per (batch, chunk-of-256).
// S_m = sum z^m, H_{m,w} = sum z^m * v_w, m=0..15.  Butterfly wave-reduce.
// ---------------------------------------------------------------------------
__global__ __attribute__((amdgpu_waves_per_eu(1, 2)))
__launch_bounds__(64) void qsa_moments_partial(
        const float* __restrict__ kv,
        float* __restrict__ mpart) {
    int blk = blockIdx.x;             // 16 batches * 8 chunks
    int b = blk >> 3, c = blk & 7;
    int lane = threadIdx.x;
    float S[NMOM], H[NMOM][6];
#pragma unroll
    for (int m = 0; m < NMOM; ++m) {
        S[m] = 0.f;
#pragma unroll
        for (int w = 0; w < 6; ++w) H[m][w] = 0.f;
    }
    const float* base = kv + ((size_t)(b * TPB + c * 256)) * 8;
#pragma unroll
    for (int r = 0; r < 4; ++r) {
        const float4* e = (const float4*)(base + (size_t)(r * 64 + lane) * 8);
        float4 e0 = e[0], e1 = e[1];
        float z = e0.x;
        float v0 = e0.y, v1 = e0.z, v2 = e0.w, v3 = e1.x, v4 = e1.y, v5 = e1.z;
        float pw = 1.f;
#pragma unroll
        for (int m = 0; m < NMOM; ++m) {
            S[m] += pw;
            H[m][0] += pw * v0; H[m][1] += pw * v1; H[m][2] += pw * v2;
            H[m][3] += pw * v3; H[m][4] += pw * v4; H[m][5] += pw * v5;
            pw *= z;
        }
    }
#pragma unroll
    for (int d = 32; d >= 1; d >>= 1) {
#pragma unroll
        for (int m = 0; m < NMOM; ++m) {
            S[m] += __shfl_xor(S[m], d, 64);
#pragma unroll
            for (int w = 0; w < 6; ++w) H[m][w] += __shfl_xor(H[m][w], d, 64);
        }
    }
    if (lane == 0) {
        float* o = mpart + (size_t)blk * 112;
#pragma unroll
        for (int m = 0; m < NMOM; ++m) {
            float* om = o + m * 7;
            om[0] = S[m];
            om[1] = H[m][0]; om[2] = H[m][1]; om[3] = H[m][2];
            om[4] = H[m][3]; om[5] = H[m][4]; om[6] = H[m][5];
        }
    }
}

// ---------------------------------------------------------------------------
// Kernel 3: fused combine + per-token evaluation (one block = 256 tokens).
// den = sum_m p_m S_m, out_w = sum_m p_m H_mw, p_m = a^m/m!.
// ---------------------------------------------------------------------------
__global__ __launch_bounds__(256) void qsa_eval(
        const float* __restrict__ zq,
        const float* __restrict__ mpart,
        float* __restrict__ out) {
    __shared__ float sm[112];
    int bk = blockIdx.x;                      // 128 blocks
    int b = bk >> 3;                          // 8 blocks per batch
    int tid = threadIdx.x;
    if (tid < 112) {
        float s = 0.f;
#pragma unroll
        for (int c = 0; c < 8; ++c) s += mpart[(size_t)(b * 8 + c) * 112 + tid];
        sm[tid] = s;
    }
    __syncthreads();

    int t = bk * 256 + tid;
    float a = zq[t];
    float den = 0.f, o0 = 0.f, o1 = 0.f, o2 = 0.f, o3 = 0.f, o4 = 0.f, o5 = 0.f;
    float pw = 1.f;
#pragma unroll
    for (int m = 0; m < NMOM; ++m) {
        const float* mm = sm + m * 7;
        den += pw * mm[0];
        o0 += pw * mm[1]; o1 += pw * mm[2]; o2 += pw * mm[3];
        o3 += pw * mm[4]; o4 += pw * mm[5]; o5 += pw * mm[6];
        pw *= a * (1.0f / (m + 1));           // p_{m+1} = p_m * a/(m+1)
    }
    float inv = 1.0f / den;
    float* o = out + (size_t)t * 6;
    float2* o2p = (float2*)o;                 // t*24B is 8-aligned
    o2p[0] = make_float2(o0 * inv, o1 * inv);
    o2p[1] = make_float2(o2 * inv, o3 * inv);
    o2p[2] = make_float2(o4 * inv, o5 * inv);
}

// ---------------------------------------------------------------------------
extern "C" void kernel_launch(void* const* d_in, const int* in_sizes, int n_in,
                              void* d_out, int out_size, void* d_ws, size_t ws_size,
                              hipStream_t stream) {
    const float* x  = (const float*)d_in[0];
    const float* pq = (const float*)d_in[1];
    const float* pk = (const float*)d_in[2];
    const float* pv = (const float*)d_in[3];
    float* w = (float*)d_ws;
    // ws: cs[512 fl] | Apack[3*16384 ushort = 24576 fl-slots] | zq | kv | mpart
    float* cs            = w;
    unsigned short* Apk  = (unsigned short*)(w + 512);
    float* zq            = w + 512 + 24576;
    float* kv            = zq + NTOK;
    float* mpart         = kv + NTOK * 8;
    float* out           = (float*)d_out;

    qsa_prep<<<1, 64, 0, stream>>>(pq, pk, pv, cs);
    qsa_prepM<<<3, 64, 0, stream>>>(cs, Apk);
    qsa_sim<<<dim3(NTOK / 64, 3), 256, 0, stream>>>(x, Apk, zq, kv);
    qsa_moments_partial<<<NBATCH * 8, 64, 0, stream>>>(kv, mpart);
    qsa_eval<<<NTOK / 256, 256, 0, stream>>>(zq, mpart, out);
}

// Round 11
// 87.133 us; speedup vs baseline: 1.7332x; 1.2971x over previous
//
#include <hip/hip_runtime.h>
#include <math.h>

#define NWIRES 6
#define DIM 64
#define NTOK 32768            // B*T = 16*2048
#define NBATCH 16
#define TPB 2048              // tokens per batch
#define NMOM 16               // Taylor order: exp(az), |az|<=sqrt(6); rem ~8e-8
#define SQRT6F 2.4494897427831781f
#define APAD 72               // padded LDS row stride for A (ushorts)

typedef short bf16x8 __attribute__((ext_vector_type(8)));
typedef float f32x4  __attribute__((ext_vector_type(4)));

__device__ __forceinline__ unsigned f2bfbits(float f) {   // RNE fp32->bf16 bits
    unsigned u = __float_as_uint(f);
    return (u + 0x7FFF + ((u >> 16) & 1)) >> 16;
}
__device__ __forceinline__ float bfbits2f(unsigned b) {
    return __uint_as_float(b << 16);
}

// ---------------------------------------------------------------------------
// Kernel 0: build A = [A_c; A_s] per circuit, bf16 hi/lo split.
// Grid (3 circuits, 2 phases): ph=0 -> cos rows 0..63, ph=1 -> sin rows 64..127.
// Column k of A_c = G * W * diag(cosd) * W e_k (R10-verified math path).
// Angle tables computed inline in LDS (folds old qsa_prep kernel).
// R10 post-mortem: single-phase version ran ~2600 serial inst at ~4cyc/inst
// (1 wave, no TLP) ~ 10+ us; 6-way split halves the chain per wave.
// ---------------------------------------------------------------------------
template<int M>
__device__ __forceinline__ void ryr(float* v, float c, float s) {
#pragma unroll
    for (int i = 0; i < DIM; ++i) {
        if (i & M) continue;
        int j = i | M;
        float a = v[i], b = v[j];
        v[i] = c * a - s * b;
        v[j] = s * a + c * b;
    }
}
template<int MC, int MT>
__device__ __forceinline__ void cnr(float* v) {
#pragma unroll
    for (int i = 0; i < DIM; ++i) {
        if (!(i & MC) || (i & MT)) continue;
        int j = i | MT;
        float t = v[i]; v[i] = v[j]; v[j] = t;
    }
}

__global__ __attribute__((amdgpu_waves_per_eu(1, 1)))
__launch_bounds__(64) void qsa_prepA(const float* __restrict__ pq,
                                     const float* __restrict__ pk,
                                     const float* __restrict__ pv,
                                     unsigned short* __restrict__ Apack) {
    int c = blockIdx.x, ph = blockIdx.y;
    int k = threadIdx.x;
    __shared__ float sT[64];
    __shared__ float sP[24];
    const float* p = (c == 0) ? pq : (c == 1 ? pk : pv);
    float d = 0.f;
#pragma unroll
    for (int j = 0; j < 6; ++j)
        d += 0.5f * p[j] * ((k & (32 >> j)) ? -1.f : 1.f);
    float sd, cd;
    sincosf(d, &sd, &cd);
    sT[k] = ph ? sd : cd;
    if (k < 12) {                         // p[6..11]=RY0, p[12..17]=RY1
        float s, cc;
        sincosf(0.5f * p[6 + k], &s, &cc);
        sP[k * 2 + 0] = cc;
        sP[k * 2 + 1] = s;
    }
    __syncthreads();

    float v[DIM];
#pragma unroll
    for (int i = 0; i < DIM; ++i)
        v[i] = (__popc(i & k) & 1) ? -sT[i] : sT[i];   // diag(T) W e_k
    // Walsh
#pragma unroll
    for (int M = 32; M >= 1; M >>= 1) {
#pragma unroll
        for (int i = 0; i < DIM; ++i) {
            if (i & M) continue;
            int j = i | M;
            float a = v[i], b = v[j];
            v[i] = a + b; v[j] = a - b;
        }
    }
    // G = RY0 layer, CNOT ring, RY1 layer
    ryr<32>(v, sP[0],  sP[1]);
    ryr<16>(v, sP[2],  sP[3]);
    ryr< 8>(v, sP[4],  sP[5]);
    ryr< 4>(v, sP[6],  sP[7]);
    ryr< 2>(v, sP[8],  sP[9]);
    ryr< 1>(v, sP[10], sP[11]);
    cnr<32,16>(v); cnr<16,8>(v); cnr<8,4>(v);
    cnr<4,2>(v);   cnr<2,1>(v);  cnr<1,32>(v);
    ryr<32>(v, sP[12], sP[13]);
    ryr<16>(v, sP[14], sP[15]);
    ryr< 8>(v, sP[16], sP[17]);
    ryr< 4>(v, sP[18], sP[19]);
    ryr< 2>(v, sP[20], sP[21]);
    ryr< 1>(v, sP[22], sP[23]);

    unsigned short* Ah = Apack + (size_t)c * 16384;
    unsigned short* Al = Ah + 8192;
#pragma unroll
    for (int r = 0; r < DIM; ++r) {
        unsigned hb = f2bfbits(v[r]);
        unsigned lb = f2bfbits(v[r] - bfbits2f(hb));
        int row = ph * 64 + r;
        Ah[row * 64 + k] = (unsigned short)hb;       // coalesced per row
        Al[row * 64 + k] = (unsigned short)lb;
    }
}

// ---------------------------------------------------------------------------
// Kernel 1: MFMA sim.  Per block: 64-token tile, one circuit (blockIdx.y).
// C[r,t] = sum_k A[r,k] x[t,k] via mfma_f32_16x16x32_bf16, bf16x3 split
// (Ah*Xh + Ah*Xl + Al*Xh) -- R10-verified layouts and epilogue.
// R10 post-mortem fixes: (1) A staged to LDS once per block (32KB coalesced),
// fragments via ds_read_b128 instead of 32 dependent per-lane global loads;
// (2) X fragments loaded DIRECTLY from global into registers (B-operand k-runs
// match x row-major exactly) -- no X LDS, no second barrier, in-register
// fp32->bf16 hi/lo conversion.
// ---------------------------------------------------------------------------
__global__ __launch_bounds__(256, 4) void qsa_sim(
        const float* __restrict__ x,
        const unsigned short* __restrict__ Apack,
        float* __restrict__ zq,
        float* __restrict__ kv) {
    __shared__ unsigned short sAh[128 * APAD];   // 18432 B
    __shared__ unsigned short sAl[128 * APAD];   // 18432 B
    int tid = threadIdx.x;
    int tbase = blockIdx.x * 64;
    int circ = blockIdx.y;

    // ---- stage A (32 KB) into LDS, coalesced uint4 ----
    const uint4* Agh = (const uint4*)(Apack + (size_t)circ * 16384);
    const uint4* Agl = (const uint4*)(Apack + (size_t)circ * 16384 + 8192);
#pragma unroll
    for (int it = 0; it < 4; ++it) {
        int i = it * 256 + tid;                  // 1024 chunks of 8 ushorts
        int r = i >> 3, ch = i & 7;
        *(uint4*)(&sAh[r * APAD + ch * 8]) = Agh[i];
        *(uint4*)(&sAl[r * APAD + ch * 8]) = Agl[i];
    }

    // ---- X fragments straight from global (overlaps with A staging) ----
    int lane = tid & 63, wv = tid >> 6;
    int q4 = lane >> 4, c16 = lane & 15;
    int mytok = wv * 16 + c16;                   // B-op col n
    const float* xr = x + ((size_t)(tbase + mytok)) * 64;
    bf16x8 xh[2], xl[2];
#pragma unroll
    for (int ks = 0; ks < 2; ++ks) {
        float4 f0 = *(const float4*)(xr + ks * 32 + q4 * 8);
        float4 f1 = *(const float4*)(xr + ks * 32 + q4 * 8 + 4);
        float ff[8] = {f0.x, f0.y, f0.z, f0.w, f1.x, f1.y, f1.z, f1.w};
#pragma unroll
        for (int e = 0; e < 8; ++e) {
            unsigned hb = f2bfbits(ff[e]);
            unsigned lb = f2bfbits(ff[e] - bfbits2f(hb));
            xh[ks][e] = (short)hb;
            xl[ks][e] = (short)lb;
        }
    }
    __syncthreads();

    f32x4 acc[8];
#pragma unroll
    for (int mt = 0; mt < 8; ++mt) acc[mt] = (f32x4){0.f, 0.f, 0.f, 0.f};

#pragma unroll
    for (int mt = 0; mt < 8; ++mt) {
        int r = mt * 16 + c16;                   // A-op row m
#pragma unroll
        for (int ks = 0; ks < 2; ++ks) {
            bf16x8 ah = *(const bf16x8*)(&sAh[r * APAD + ks * 32 + q4 * 8]);
            bf16x8 al = *(const bf16x8*)(&sAl[r * APAD + ks * 32 + q4 * 8]);
            acc[mt] = __builtin_amdgcn_mfma_f32_16x16x32_bf16(ah, xh[ks], acc[mt], 0, 0, 0);
            acc[mt] = __builtin_amdgcn_mfma_f32_16x16x32_bf16(ah, xl[ks], acc[mt], 0, 0, 0);
            acc[mt] = __builtin_amdgcn_mfma_f32_16x16x32_bf16(al, xh[ks], acc[mt], 0, 0, 0);
        }
    }

    // ---- epilogue: p_r = dc^2 + ds^2, masked sums, 4-lane combine ----
    float n = 0.f, s0 = 0.f, s1 = 0.f, s2 = 0.f, s3 = 0.f, s4 = 0.f, s5 = 0.f;
    float f2 = (q4 < 2) ? 1.f : 0.f;             // r bit3 == 0
    float f3 = (q4 & 1) ? 0.f : 1.f;             // r bit2 == 0
#pragma unroll
    for (int mt = 0; mt < 4; ++mt) {
#pragma unroll
        for (int rg = 0; rg < 4; ++rg) {
            float dc = acc[mt][rg];              // row r = mt*16 + q4*4 + rg
            float ds = acc[mt + 4][rg];          // row r + 64
            float p = dc * dc + ds * ds;
            n += p;
            if (!(mt & 2)) s0 += p;              // bit5
            if (!(mt & 1)) s1 += p;              // bit4
            s2 += f2 * p;                        // bit3
            s3 += f3 * p;                        // bit2
            if (!(rg & 2)) s4 += p;              // bit1
            if (!(rg & 1)) s5 += p;              // bit0
        }
    }
#pragma unroll
    for (int d = 16; d <= 32; d <<= 1) {
        n  += __shfl_xor(n,  d, 64);
        s0 += __shfl_xor(s0, d, 64);
        s1 += __shfl_xor(s1, d, 64);
        s2 += __shfl_xor(s2, d, 64);
        s3 += __shfl_xor(s3, d, 64);
        s4 += __shfl_xor(s4, d, 64);
        s5 += __shfl_xor(s5, d, 64);
    }
    if (q4 == 0) {
        int t = tbase + mytok;
        float inv = 1.0f / n;
        if (circ == 0) {
            zq[t] = SQRT6F * (2.f * s0 - n) * inv;     // a_t, natural-exp scale
        } else if (circ == 1) {
            kv[(size_t)t * 8] = (2.f * s0 - n) * inv;
        } else {
            float* o = kv + (size_t)t * 8;
            o[1] = (2.f*s0 - n) * inv;
            o[2] = (2.f*s1 - n) * inv;
            o[3] = (2.f*s2 - n) * inv;
            o[4] = (2.f*s3 - n) * inv;
            o[5] = (2.f*s4 - n) * inv;
            o[6] = (2.f*s5 - n) * inv;
            o[7] = 0.f;
        }
    }
}

// ---------------------------------------------------------------------------
// Kernel 2: partial power moments per (batch, chunk-of-256).
// S_m = sum z^m, H_{m,w} = sum z^m * v_w, m=0..15.  Butterfly wave-reduce.
// ---------------------------------------------------------------------------
__global__ __attribute__((amdgpu_waves_per_eu(1, 2)))
__launch_bounds__(64) void qsa_moments_partial(
        const float* __restrict__ kv,
        float* __restrict__ mpart) {
    int blk = blockIdx.x;             // 16 batches * 8 chunks
    int b = blk >> 3, c = blk & 7;
    int lane = threadIdx.x;
    float S[NMOM], H[NMOM][6];
#pragma unroll
    for (int m = 0; m < NMOM; ++m) {
        S[m] = 0.f;
#pragma unroll
        for (int w = 0; w < 6; ++w) H[m][w] = 0.f;
    }
    const float* base = kv + ((size_t)(b * TPB + c * 256)) * 8;
#pragma unroll
    for (int r = 0; r < 4; ++r) {
        const float4* e = (const float4*)(base + (size_t)(r * 64 + lane) * 8);
        float4 e0 = e[0], e1 = e[1];
        float z = e0.x;
        float v0 = e0.y, v1 = e0.z, v2 = e0.w, v3 = e1.x, v4 = e1.y, v5 = e1.z;
        float pw = 1.f;
#pragma unroll
        for (int m = 0; m < NMOM; ++m) {
            S[m] += pw;
            H[m][0] += pw * v0; H[m][1] += pw * v1; H[m][2] += pw * v2;
            H[m][3] += pw * v3; H[m][4] += pw * v4; H[m][5] += pw * v5;
            pw *= z;
        }
    }
#pragma unroll
    for (int d = 32; d >= 1; d >>= 1) {
#pragma unroll
        for (int m = 0; m < NMOM; ++m) {
            S[m] += __shfl_xor(S[m], d, 64);
#pragma unroll
            for (int w = 0; w < 6; ++w) H[m][w] += __shfl_xor(H[m][w], d, 64);
        }
    }
    if (lane == 0) {
        float* o = mpart + (size_t)blk * 112;
#pragma unroll
        for (int m = 0; m < NMOM; ++m) {
            float* om = o + m * 7;
            om[0] = S[m];
            om[1] = H[m][0]; om[2] = H[m][1]; om[3] = H[m][2];
            om[4] = H[m][3]; om[5] = H[m][4]; om[6] = H[m][5];
        }
    }
}

// ---------------------------------------------------------------------------
// Kernel 3: fused combine + per-token evaluation (one block = 256 tokens).
// den = sum_m p_m S_m, out_w = sum_m p_m H_mw, p_m = a^m/m!.
// ---------------------------------------------------------------------------
__global__ __launch_bounds__(256) void qsa_eval(
        const float* __restrict__ zq,
        const float* __restrict__ mpart,
        float* __restrict__ out) {
    __shared__ float sm[112];
    int bk = blockIdx.x;                      // 128 blocks
    int b = bk >> 3;                          // 8 blocks per batch
    int tid = threadIdx.x;
    if (tid < 112) {
        float s = 0.f;
#pragma unroll
        for (int c = 0; c < 8; ++c) s += mpart[(size_t)(b * 8 + c) * 112 + tid];
        sm[tid] = s;
    }
    __syncthreads();

    int t = bk * 256 + tid;
    float a = zq[t];
    float den = 0.f, o0 = 0.f, o1 = 0.f, o2 = 0.f, o3 = 0.f, o4 = 0.f, o5 = 0.f;
    float pw = 1.f;
#pragma unroll
    for (int m = 0; m < NMOM; ++m) {
        const float* mm = sm + m * 7;
        den += pw * mm[0];
        o0 += pw * mm[1]; o1 += pw * mm[2]; o2 += pw * mm[3];
        o3 += pw * mm[4]; o4 += pw * mm[5]; o5 += pw * mm[6];
        pw *= a * (1.0f / (m + 1));           // p_{m+1} = p_m * a/(m+1)
    }
    float inv = 1.0f / den;
    float* o = out + (size_t)t * 6;
    float2* o2p = (float2*)o;                 // t*24B is 8-aligned
    o2p[0] = make_float2(o0 * inv, o1 * inv);
    o2p[1] = make_float2(o2 * inv, o3 * inv);
    o2p[2] = make_float2(o4 * inv, o5 * inv);
}

// ---------------------------------------------------------------------------
extern "C" void kernel_launch(void* const* d_in, const int* in_sizes, int n_in,
                              void* d_out, int out_size, void* d_ws, size_t ws_size,
                              hipStream_t stream) {
    const float* x  = (const float*)d_in[0];
    const float* pq = (const float*)d_in[1];
    const float* pk = (const float*)d_in[2];
    const float* pv = (const float*)d_in[3];
    float* w = (float*)d_ws;
    // ws: Apack[3*16384 ushort = 24576 fl-slots] | zq | kv | mpart
    unsigned short* Apk  = (unsigned short*)w;
    float* zq            = w + 24576;
    float* kv            = zq + NTOK;
    float* mpart         = kv + NTOK * 8;
    float* out           = (float*)d_out;

    qsa_prepA<<<dim3(3, 2), 64, 0, stream>>>(pq, pk, pv, Apk);
    qsa_sim<<<dim3(NTOK / 64, 3), 256, 0, stream>>>(x, Apk, zq, kv);
    qsa_moments_partial<<<NBATCH * 8, 64, 0, stream>>>(kv, mpart);
    qsa_eval<<<NTOK / 256, 256, 0, stream>>>(zq, mpart, out);
}

// Round 12
// 86.862 us; speedup vs baseline: 1.7386x; 1.0031x over previous
//
#include <hip/hip_runtime.h>
#include <math.h>

#define NWIRES 6
#define DIM 64
#define NTOK 32768            // B*T = 16*2048
#define NBATCH 16
#define TPB 2048              // tokens per batch
#define NMOM 16               // Taylor order: exp(az), |az|<=sqrt(6); rem ~8e-8
#define SQRT6F 2.4494897427831781f
#define APAD 76               // LDS row stride (ushorts) = 38 dwords: bank term
                              // 6*c16+4*q4 -> <=2 lanes/bank/phase (conflict-free);
                              // 72 gave 4*((c16+q4)%8) -> 8-way (R11 post-mortem)

typedef short bf16x8 __attribute__((ext_vector_type(8)));
typedef float f32x4  __attribute__((ext_vector_type(4)));

__device__ __forceinline__ unsigned f2bfbits(float f) {   // RNE fp32->bf16 bits
    unsigned u = __float_as_uint(f);
    return (u + 0x7FFF + ((u >> 16) & 1)) >> 16;
}
__device__ __forceinline__ float bfbits2f(unsigned b) {
    return __uint_as_float(b << 16);
}

// ---------------------------------------------------------------------------
// Kernel 0: build A = [A_c; A_s] per circuit, bf16 hi/lo split.
// Grid (3 circuits, 2 phases): ph=0 -> cos rows 0..63, ph=1 -> sin rows 64..127.
// Column k of A_c = G * W * diag(cosd) * W e_k (R10/R11-verified math path).
// ---------------------------------------------------------------------------
template<int M>
__device__ __forceinline__ void ryr(float* v, float c, float s) {
#pragma unroll
    for (int i = 0; i < DIM; ++i) {
        if (i & M) continue;
        int j = i | M;
        float a = v[i], b = v[j];
        v[i] = c * a - s * b;
        v[j] = s * a + c * b;
    }
}
template<int MC, int MT>
__device__ __forceinline__ void cnr(float* v) {
#pragma unroll
    for (int i = 0; i < DIM; ++i) {
        if (!(i & MC) || (i & MT)) continue;
        int j = i | MT;
        float t = v[i]; v[i] = v[j]; v[j] = t;
    }
}

__global__ __attribute__((amdgpu_waves_per_eu(1, 1)))
__launch_bounds__(64) void qsa_prepA(const float* __restrict__ pq,
                                     const float* __restrict__ pk,
                                     const float* __restrict__ pv,
                                     unsigned short* __restrict__ Apack) {
    int c = blockIdx.x, ph = blockIdx.y;
    int k = threadIdx.x;
    __shared__ float sT[64];
    __shared__ float sP[24];
    const float* p = (c == 0) ? pq : (c == 1 ? pk : pv);
    float d = 0.f;
#pragma unroll
    for (int j = 0; j < 6; ++j)
        d += 0.5f * p[j] * ((k & (32 >> j)) ? -1.f : 1.f);
    float sd, cd;
    sincosf(d, &sd, &cd);
    sT[k] = ph ? sd : cd;
    if (k < 12) {                         // p[6..11]=RY0, p[12..17]=RY1
        float s, cc;
        sincosf(0.5f * p[6 + k], &s, &cc);
        sP[k * 2 + 0] = cc;
        sP[k * 2 + 1] = s;
    }
    __syncthreads();

    float v[DIM];
#pragma unroll
    for (int i = 0; i < DIM; ++i)
        v[i] = (__popc(i & k) & 1) ? -sT[i] : sT[i];   // diag(T) W e_k
    // Walsh
#pragma unroll
    for (int M = 32; M >= 1; M >>= 1) {
#pragma unroll
        for (int i = 0; i < DIM; ++i) {
            if (i & M) continue;
            int j = i | M;
            float a = v[i], b = v[j];
            v[i] = a + b; v[j] = a - b;
        }
    }
    // G = RY0 layer, CNOT ring, RY1 layer
    ryr<32>(v, sP[0],  sP[1]);
    ryr<16>(v, sP[2],  sP[3]);
    ryr< 8>(v, sP[4],  sP[5]);
    ryr< 4>(v, sP[6],  sP[7]);
    ryr< 2>(v, sP[8],  sP[9]);
    ryr< 1>(v, sP[10], sP[11]);
    cnr<32,16>(v); cnr<16,8>(v); cnr<8,4>(v);
    cnr<4,2>(v);   cnr<2,1>(v);  cnr<1,32>(v);
    ryr<32>(v, sP[12], sP[13]);
    ryr<16>(v, sP[14], sP[15]);
    ryr< 8>(v, sP[16], sP[17]);
    ryr< 4>(v, sP[18], sP[19]);
    ryr< 2>(v, sP[20], sP[21]);
    ryr< 1>(v, sP[22], sP[23]);

    unsigned short* Ah = Apack + (size_t)c * 16384;
    unsigned short* Al = Ah + 8192;
#pragma unroll
    for (int r = 0; r < DIM; ++r) {
        unsigned hb = f2bfbits(v[r]);
        unsigned lb = f2bfbits(v[r] - bfbits2f(hb));
        int row = ph * 64 + r;
        Ah[row * 64 + k] = (unsigned short)hb;       // coalesced per row
        Al[row * 64 + k] = (unsigned short)lb;
    }
}

// ---------------------------------------------------------------------------
// Kernel 1: MFMA sim.  Per block: 64-token tile, one circuit (blockIdx.y).
// C[r,t] = sum_k A[r,k] x[t,k] via mfma_f32_16x16x32_bf16, bf16x3 split
// (Ah*Xh + Ah*Xl + Al*Xh) -- verified layouts and epilogue (R10/R11).
// R12 change: APAD 76 (conflict-free banks); all LDS access via uint2 (8B)
// because 152B rows leave odd rows 8B-aligned (no b128).
// ---------------------------------------------------------------------------
__global__ __launch_bounds__(256, 4) void qsa_sim(
        const float* __restrict__ x,
        const unsigned short* __restrict__ Apack,
        float* __restrict__ zq,
        float* __restrict__ kv) {
    __shared__ unsigned short sAh[128 * APAD];   // 19456 B
    __shared__ unsigned short sAl[128 * APAD];   // 19456 B
    int tid = threadIdx.x;
    int tbase = blockIdx.x * 64;
    int circ = blockIdx.y;

    // ---- stage A (32 KB) into LDS, coalesced; uint2 pairs (8B-aligned) ----
    const uint4* Agh = (const uint4*)(Apack + (size_t)circ * 16384);
    const uint4* Agl = (const uint4*)(Apack + (size_t)circ * 16384 + 8192);
#pragma unroll
    for (int it = 0; it < 4; ++it) {
        int i = it * 256 + tid;                  // 1024 chunks of 8 ushorts
        int r = i >> 3, ch = i & 7;
        uint4 qh = Agh[i], ql = Agl[i];
        uint2* dh = (uint2*)(&sAh[r * APAD + ch * 8]);
        uint2* dl = (uint2*)(&sAl[r * APAD + ch * 8]);
        dh[0] = make_uint2(qh.x, qh.y);
        dh[1] = make_uint2(qh.z, qh.w);
        dl[0] = make_uint2(ql.x, ql.y);
        dl[1] = make_uint2(ql.z, ql.w);
    }

    // ---- X fragments straight from global (overlaps with A staging) ----
    int lane = tid & 63, wv = tid >> 6;
    int q4 = lane >> 4, c16 = lane & 15;
    int mytok = wv * 16 + c16;                   // B-op col n
    const float* xr = x + ((size_t)(tbase + mytok)) * 64;
    bf16x8 xh[2], xl[2];
#pragma unroll
    for (int ks = 0; ks < 2; ++ks) {
        float4 f0 = *(const float4*)(xr + ks * 32 + q4 * 8);
        float4 f1 = *(const float4*)(xr + ks * 32 + q4 * 8 + 4);
        float ff[8] = {f0.x, f0.y, f0.z, f0.w, f1.x, f1.y, f1.z, f1.w};
#pragma unroll
        for (int e = 0; e < 8; ++e) {
            unsigned hb = f2bfbits(ff[e]);
            unsigned lb = f2bfbits(ff[e] - bfbits2f(hb));
            xh[ks][e] = (short)hb;
            xl[ks][e] = (short)lb;
        }
    }
    __syncthreads();

    f32x4 acc[8];
#pragma unroll
    for (int mt = 0; mt < 8; ++mt) acc[mt] = (f32x4){0.f, 0.f, 0.f, 0.f};

#pragma unroll
    for (int mt = 0; mt < 8; ++mt) {
        int r = mt * 16 + c16;                   // A-op row m
#pragma unroll
        for (int ks = 0; ks < 2; ++ks) {
            const uint2* ph = (const uint2*)(&sAh[r * APAD + ks * 32 + q4 * 8]);
            const uint2* pl = (const uint2*)(&sAl[r * APAD + ks * 32 + q4 * 8]);
            uint2 h0 = ph[0], h1 = ph[1];
            uint2 l0 = pl[0], l1 = pl[1];
            union { uint2 u[2]; bf16x8 v; } ua, ub;
            ua.u[0] = h0; ua.u[1] = h1;
            ub.u[0] = l0; ub.u[1] = l1;
            bf16x8 ah = ua.v, al = ub.v;
            acc[mt] = __builtin_amdgcn_mfma_f32_16x16x32_bf16(ah, xh[ks], acc[mt], 0, 0, 0);
            acc[mt] = __builtin_amdgcn_mfma_f32_16x16x32_bf16(ah, xl[ks], acc[mt], 0, 0, 0);
            acc[mt] = __builtin_amdgcn_mfma_f32_16x16x32_bf16(al, xh[ks], acc[mt], 0, 0, 0);
        }
    }

    // ---- epilogue: p_r = dc^2 + ds^2, masked sums, 4-lane combine ----
    float n = 0.f, s0 = 0.f, s1 = 0.f, s2 = 0.f, s3 = 0.f, s4 = 0.f, s5 = 0.f;
    float f2 = (q4 < 2) ? 1.f : 0.f;             // r bit3 == 0
    float f3 = (q4 & 1) ? 0.f : 1.f;             // r bit2 == 0
#pragma unroll
    for (int mt = 0; mt < 4; ++mt) {
#pragma unroll
        for (int rg = 0; rg < 4; ++rg) {
            float dc = acc[mt][rg];              // row r = mt*16 + q4*4 + rg
            float ds = acc[mt + 4][rg];          // row r + 64
            float p = dc * dc + ds * ds;
            n += p;
            if (!(mt & 2)) s0 += p;              // bit5
            if (!(mt & 1)) s1 += p;              // bit4
            s2 += f2 * p;                        // bit3
            s3 += f3 * p;                        // bit2
            if (!(rg & 2)) s4 += p;              // bit1
            if (!(rg & 1)) s5 += p;              // bit0
        }
    }
#pragma unroll
    for (int d = 16; d <= 32; d <<= 1) {
        n  += __shfl_xor(n,  d, 64);
        s0 += __shfl_xor(s0, d, 64);
        s1 += __shfl_xor(s1, d, 64);
        s2 += __shfl_xor(s2, d, 64);
        s3 += __shfl_xor(s3, d, 64);
        s4 += __shfl_xor(s4, d, 64);
        s5 += __shfl_xor(s5, d, 64);
    }
    if (q4 == 0) {
        int t = tbase + mytok;
        float inv = 1.0f / n;
        if (circ == 0) {
            zq[t] = SQRT6F * (2.f * s0 - n) * inv;     // a_t, natural-exp scale
        } else if (circ == 1) {
            kv[(size_t)t * 8] = (2.f * s0 - n) * inv;
        } else {
            float* o = kv + (size_t)t * 8;
            o[1] = (2.f*s0 - n) * inv;
            o[2] = (2.f*s1 - n) * inv;
            o[3] = (2.f*s2 - n) * inv;
            o[4] = (2.f*s3 - n) * inv;
            o[5] = (2.f*s4 - n) * inv;
            o[6] = (2.f*s5 - n) * inv;
            o[7] = 0.f;
        }
    }
}

// ---------------------------------------------------------------------------
// Kernel 2: partial power moments per (batch, chunk-of-256).
// S_m = sum z^m, H_{m,w} = sum z^m * v_w, m=0..15.  Butterfly wave-reduce.
// ---------------------------------------------------------------------------
__global__ __attribute__((amdgpu_waves_per_eu(1, 2)))
__launch_bounds__(64) void qsa_moments_partial(
        const float* __restrict__ kv,
        float* __restrict__ mpart) {
    int blk = blockIdx.x;             // 16 batches * 8 chunks
    int b = blk >> 3, c = blk & 7;
    int lane = threadIdx.x;
    float S[NMOM], H[NMOM][6];
#pragma unroll
    for (int m = 0; m < NMOM; ++m) {
        S[m] = 0.f;
#pragma unroll
        for (int w = 0; w < 6; ++w) H[m][w] = 0.f;
    }
    const float* base = kv + ((size_t)(b * TPB + c * 256)) * 8;
#pragma unroll
    for (int r = 0; r < 4; ++r) {
        const float4* e = (const float4*)(base + (size_t)(r * 64 + lane) * 8);
        float4 e0 = e[0], e1 = e[1];
        float z = e0.x;
        float v0 = e0.y, v1 = e0.z, v2 = e0.w, v3 = e1.x, v4 = e1.y, v5 = e1.z;
        float pw = 1.f;
#pragma unroll
        for (int m = 0; m < NMOM; ++m) {
            S[m] += pw;
            H[m][0] += pw * v0; H[m][1] += pw * v1; H[m][2] += pw * v2;
            H[m][3] += pw * v3; H[m][4] += pw * v4; H[m][5] += pw * v5;
            pw *= z;
        }
    }
#pragma unroll
    for (int d = 32; d >= 1; d >>= 1) {
#pragma unroll
        for (int m = 0; m < NMOM; ++m) {
            S[m] += __shfl_xor(S[m], d, 64);
#pragma unroll
            for (int w = 0; w < 6; ++w) H[m][w] += __shfl_xor(H[m][w], d, 64);
        }
    }
    if (lane == 0) {
        float* o = mpart + (size_t)blk * 112;
#pragma unroll
        for (int m = 0; m < NMOM; ++m) {
            float* om = o + m * 7;
            om[0] = S[m];
            om[1] = H[m][0]; om[2] = H[m][1]; om[3] = H[m][2];
            om[4] = H[m][3]; om[5] = H[m][4]; om[6] = H[m][5];
        }
    }
}

// ---------------------------------------------------------------------------
// Kernel 3: fused combine + per-token evaluation (one block = 256 tokens).
// den = sum_m p_m S_m, out_w = sum_m p_m H_mw, p_m = a^m/m!.
// ---------------------------------------------------------------------------
__global__ __launch_bounds__(256) void qsa_eval(
        const float* __restrict__ zq,
        const float* __restrict__ mpart,
        float* __restrict__ out) {
    __shared__ float sm[112];
    int bk = blockIdx.x;                      // 128 blocks
    int b = bk >> 3;                          // 8 blocks per batch
    int tid = threadIdx.x;
    if (tid < 112) {
        float s = 0.f;
#pragma unroll
        for (int c = 0; c < 8; ++c) s += mpart[(size_t)(b * 8 + c) * 112 + tid];
        sm[tid] = s;
    }
    __syncthreads();

    int t = bk * 256 + tid;
    float a = zq[t];
    float den = 0.f, o0 = 0.f, o1 = 0.f, o2 = 0.f, o3 = 0.f, o4 = 0.f, o5 = 0.f;
    float pw = 1.f;
#pragma unroll
    for (int m = 0; m < NMOM; ++m) {
        const float* mm = sm + m * 7;
        den += pw * mm[0];
        o0 += pw * mm[1]; o1 += pw * mm[2]; o2 += pw * mm[3];
        o3 += pw * mm[4]; o4 += pw * mm[5]; o5 += pw * mm[6];
        pw *= a * (1.0f / (m + 1));           // p_{m+1} = p_m * a/(m+1)
    }
    float inv = 1.0f / den;
    float* o = out + (size_t)t * 6;
    float2* o2p = (float2*)o;                 // t*24B is 8-aligned
    o2p[0] = make_float2(o0 * inv, o1 * inv);
    o2p[1] = make_float2(o2 * inv, o3 * inv);
    o2p[2] = make_float2(o4 * inv, o5 * inv);
}

// ---------------------------------------------------------------------------
extern "C" void kernel_launch(void* const* d_in, const int* in_sizes, int n_in,
                              void* d_out, int out_size, void* d_ws, size_t ws_size,
                              hipStream_t stream) {
    const float* x  = (const float*)d_in[0];
    const float* pq = (const float*)d_in[1];
    const float* pk = (const float*)d_in[2];
    const float* pv = (const float*)d_in[3];
    float* w = (float*)d_ws;
    // ws: Apack[3*16384 ushort = 24576 fl-slots] | zq | kv | mpart
    unsigned short* Apk  = (unsigned short*)w;
    float* zq            = w + 24576;
    float* kv            = zq + NTOK;
    float* mpart         = kv + NTOK * 8;
    float* out           = (float*)d_out;

    qsa_prepA<<<dim3(3, 2), 64, 0, stream>>>(pq, pk, pv, Apk);
    qsa_sim<<<dim3(NTOK / 64, 3), 256, 0, stream>>>(x, Apk, zq, kv);
    qsa_moments_partial<<<NBATCH * 8, 64, 0, stream>>>(kv, mpart);
    qsa_eval<<<NTOK / 256, 256, 0, stream>>>(zq, mpart, out);
}